// Round 16
// baseline (957.119 us; speedup 1.0000x reference)
//
#include <hip/hip_runtime.h>
#include <cstdint>

#define DEV static __device__ __forceinline__

typedef unsigned short u16;
typedef __bf16 bf16x8 __attribute__((ext_vector_type(8)));
typedef float f32x4 __attribute__((ext_vector_type(4)));
typedef float f32x16 __attribute__((ext_vector_type(16)));
typedef unsigned short u16x4 __attribute__((ext_vector_type(4)));

constexpr int V = 32000, D = 1024, H = 16, L = 4, F = 4096, T = 1024, B = 2;
constexpr int HD = 64;

DEV u16 f2bf(float f) {
    union { float f; uint32_t i; } c; c.f = f;
    uint32_t x = c.i;
    return (u16)((x + 0x7fffu + ((x >> 16) & 1u)) >> 16);
}
DEV float bf2f(u16 u) {
    union { uint32_t i; float f; } c; c.i = ((uint32_t)u) << 16; return c.f;
}
DEV bf16x8 ld8(const u16* p) { return *reinterpret_cast<const bf16x8*>(p); }

DEV void gl16(const void* g, void* l) {
    __builtin_amdgcn_global_load_lds((const __attribute__((address_space(1))) void*)g,
                                     (__attribute__((address_space(3))) void*)l, 16, 0, 0);
}

// ---- batched transpose+cast device body: one 32x128 strip per block ----
DEV void castT4_dev(int t, int x, int y, u16 (*tl)[33],
        const float* __restrict__ Wqkv, const float* __restrict__ Wproj,
        const float* __restrict__ W1, const float* __restrict__ W2,
        u16* __restrict__ wt) {
    const float* src; u16* dst; int Rr, Cc;
    if (t < 768)       { src = Wqkv;  dst = wt;                       Rr = D; Cc = 3 * D; }
    else if (t < 1024) { src = Wproj; dst = wt + 3 * D * D;           Rr = D; Cc = D; t -= 768; }
    else if (t < 2048) { src = W1;    dst = wt + 4 * D * D;           Rr = D; Cc = F; t -= 1024; }
    else               { src = W2;    dst = wt + 4 * D * D + D * F;   Rr = F; Cc = D; t -= 2048; }
    int colStrips = Cc >> 7;
    int r0 = (t / colStrips) * 32;
    int c0 = (t % colStrips) * 128;
    for (int i = 0; i < 4; i++) {
        int cc = c0 + i * 32;
        __syncthreads();
#pragma unroll
        for (int j = 0; j < 4; j++)
            tl[y + j * 8][x] = f2bf(src[(size_t)(r0 + y + j * 8) * Cc + cc + x]);
        __syncthreads();
#pragma unroll
        for (int j = 0; j < 4; j++)
            dst[(size_t)(cc + y + j * 8) * Rr + r0 + x] = tl[x][y + j * 8];
    }
}

// ---------------- embedding + ln1(layer0), merged with castT4(layer0) ----------------
__global__ __launch_bounds__(256) void k_emblnT(const int* __restrict__ tok,
        const float* __restrict__ emb, const float* __restrict__ pe,
        const float* __restrict__ g, const float* __restrict__ b,
        float* __restrict__ x, u16* __restrict__ out,
        const float* __restrict__ Wqkv, const float* __restrict__ Wproj,
        const float* __restrict__ W1, const float* __restrict__ W2,
        u16* __restrict__ wt) {
    __shared__ u16 tl[32][33];
    __shared__ float ps[4], ps2[4];
    int row = blockIdx.x, tid = threadIdx.x;
    if (row >= B * T) {
        castT4_dev(row - B * T, tid & 31, tid >> 5, tl, Wqkv, Wproj, W1, W2, wt);
        return;
    }
    int t = row & (T - 1);
    int vv = tok[row];
    f32x4 v = ((const f32x4*)(emb + (size_t)vv * D))[tid] + ((const f32x4*)(pe + (size_t)t * D))[tid];
    ((f32x4*)(x + (size_t)row * D))[tid] = v;
    float s = v[0] + v[1] + v[2] + v[3];
    float s2 = v[0]*v[0] + v[1]*v[1] + v[2]*v[2] + v[3]*v[3];
#pragma unroll
    for (int m = 1; m < 64; m <<= 1) { s += __shfl_xor(s, m); s2 += __shfl_xor(s2, m); }
    int wave = tid >> 6;
    if ((tid & 63) == 0) { ps[wave] = s; ps2[wave] = s2; }
    __syncthreads();
    s = ps[0] + ps[1] + ps[2] + ps[3];
    s2 = ps2[0] + ps2[1] + ps2[2] + ps2[3];
    float mean = s * (1.f / D);
    float var = s2 * (1.f / D) - mean * mean;
    float r = rsqrtf(var + 1e-5f);
    f32x4 gg = ((const f32x4*)g)[tid];
    f32x4 bb = ((const f32x4*)b)[tid];
    u16x4 o;
#pragma unroll
    for (int j = 0; j < 4; j++) o[j] = f2bf((v[j] - mean) * r * gg[j] + bb[j]);
    ((u16x4*)(out + (size_t)row * D))[tid] = o;
}

// ------- splitK reduce (bf16 partials) + bias + residual + LayerNorm (+castT4) -------
template <int S, bool DOCAST, bool WX>
__global__ __launch_bounds__(256) void k_redlnT(const u16* __restrict__ pp,
        const float* __restrict__ bias, float* __restrict__ x,
        const float* __restrict__ g, const float* __restrict__ b,
        u16* __restrict__ out,
        const float* __restrict__ Wqkv, const float* __restrict__ Wproj,
        const float* __restrict__ W1, const float* __restrict__ W2,
        u16* __restrict__ wt) {
    __shared__ u16 tl[32][33];
    __shared__ float ps[4], ps2[4];
    int row = blockIdx.x, tid = threadIdx.x;
    if (DOCAST && row >= B * T) {
        castT4_dev(row - B * T, tid & 31, tid >> 5, tl, Wqkv, Wproj, W1, W2, wt);
        return;
    }
    f32x4 v = ((const f32x4*)(x + (size_t)row * D))[tid];
#pragma unroll
    for (int s = 0; s < S; s++) {
        u16x4 pk = ((const u16x4*)(pp + ((size_t)s * (B * T) + row) * D))[tid];
#pragma unroll
        for (int j = 0; j < 4; j++) v[j] += bf2f(pk[j]);
    }
    v += ((const f32x4*)bias)[tid];
    if (WX) ((f32x4*)(x + (size_t)row * D))[tid] = v;
    float s = v[0] + v[1] + v[2] + v[3];
    float s2 = v[0]*v[0] + v[1]*v[1] + v[2]*v[2] + v[3]*v[3];
#pragma unroll
    for (int m = 1; m < 64; m <<= 1) { s += __shfl_xor(s, m); s2 += __shfl_xor(s2, m); }
    int wave = tid >> 6;
    if ((tid & 63) == 0) { ps[wave] = s; ps2[wave] = s2; }
    __syncthreads();
    s = ps[0] + ps[1] + ps[2] + ps[3];
    s2 = ps2[0] + ps2[1] + ps2[2] + ps2[3];
    float mean = s * (1.f / D);
    float var = s2 * (1.f / D) - mean * mean;
    float r = rsqrtf(var + 1e-5f);
    f32x4 gg = ((const f32x4*)g)[tid];
    f32x4 bb = ((const f32x4*)b)[tid];
    u16x4 o;
#pragma unroll
    for (int j = 0; j < 4; j++) o[j] = f2bf((v[j] - mean) * r * gg[j] + bb[j]);
    ((u16x4*)(out + (size_t)row * D))[tid] = o;
}

// ---- shared pipeline helpers (swizzle is a size-independent involution) ----
DEV bf16x8 ldf(const u16* half, int row, int lhi) {
    int lb = row * 64 + lhi * 16;
    lb ^= ((lb >> 9) & 1) << 5;
    return *(const bf16x8*)((const char*)half + lb);
}
DEV bf16x8 ldf32(const u16* half, int row, int kb) {   // kb = byte offset within 64B row
    int lb = row * 64 + kb;
    lb ^= ((lb >> 9) & 1) << 5;
    return *(const bf16x8*)((const char*)half + lb);
}
DEV void stg(const u16* gb, int ld, int kc, u16* dstBase, int wave, int lane) {
#pragma unroll
    for (int i = 0; i < 2; i++) {
        int p = (wave * 2 + i) * 64 + lane;
        int l = p ^ (((p >> 5) & 1) << 1);
        gl16(gb + (size_t)(l >> 2) * ld + kc + (l & 3) * 8, dstBase + (wave * 2 + i) * 512);
    }
}
#define SB_BAR() do { __builtin_amdgcn_sched_barrier(0); __builtin_amdgcn_s_barrier(); } while (0)

// ------- 128x128 BK=64 merged 2-phase GEMM, 32x32x16 MFMA (4 waves, 8 MFMA/phase) -----
// Same staging/ledger as the validated 16x16 version; only LDS->reg + MFMA + epilogue
// remapped to the 32x32 fragment layout (C/D: col=lane&31, row=(reg&3)+8*(reg>>2)+4*(lane>>5)).
template <int EPI, bool VT>
__global__ __launch_bounds__(256, 2) void k_gemm4(
        const u16* __restrict__ A, int lda,
        const u16* __restrict__ Bt, int ldb,
        const float* __restrict__ bias,
        void* __restrict__ Cv, int ldc, int K, u16* __restrict__ vT) {
    __shared__ u16 lds[2][4][128 * 32];   // [buf][Ak0,Bk0,Ak1,Bk1]
    int gm = gridDim.x, nwg = gm * gridDim.y;
    int orig = blockIdx.y * gm + blockIdx.x;
    int xcd = orig & 7, idx = orig >> 3;
    int q = nwg >> 3, rr = nwg & 7;
    int wg = (xcd < rr ? xcd * (q + 1) : rr * (q + 1) + (xcd - rr) * q) + idx;
    int m0 = (wg % gm) * 128, n0 = (wg / gm) * 128;
    int koff = (EPI == 4) ? blockIdx.z * K : 0;
    int tid = threadIdx.x, wave = tid >> 6, lane = tid & 63;
    int l31 = lane & 31, lk = lane >> 5;
    int wm = wave >> 1, wn = wave & 1;
    const u16* Ab = A + (size_t)m0 * lda;
    const u16* Bb = Bt + (size_t)n0 * ldb;
    int nk = K >> 6;
    f32x16 acc[2][2] = {};
    stg(Ab, lda, koff + 0,   &lds[0][0][0], wave, lane);
    stg(Bb, ldb, koff + 0,   &lds[0][1][0], wave, lane);
    stg(Ab, lda, koff + 32,  &lds[0][2][0], wave, lane);
    stg(Bb, ldb, koff + 32,  &lds[0][3][0], wave, lane);
    stg(Ab, lda, koff + 64,  &lds[1][0][0], wave, lane);
    stg(Ab, lda, koff + 96,  &lds[1][2][0], wave, lane);
    asm volatile("s_waitcnt vmcnt(4)");
    SB_BAR();
    for (int t = 0; t < nk; ++t) {
        const int bf = t & 1;
        bf16x8 a[2][4], bfr[4];
        // ---- phase 1': A all 4 k-chunks + B ni=0; stage B(t+1); 8 MFMA ----
#pragma unroll
        for (int mi = 0; mi < 2; mi++)
#pragma unroll
            for (int c = 0; c < 4; c++)
                a[mi][c] = ldf32(&lds[bf][(c < 2) ? 0 : 2][0],
                                 wm * 64 + mi * 32 + l31, (c & 1) * 32 + lk * 16);
#pragma unroll
        for (int c = 0; c < 4; c++)
            bfr[c] = ldf32(&lds[bf][(c < 2) ? 1 : 3][0],
                           wn * 64 + l31, (c & 1) * 32 + lk * 16);
        if (t + 1 < nk) {
            stg(Bb, ldb, koff + (t + 1) * 64,      &lds[bf ^ 1][1][0], wave, lane);
            stg(Bb, ldb, koff + (t + 1) * 64 + 32, &lds[bf ^ 1][3][0], wave, lane);
        }
        __builtin_amdgcn_s_setprio(1);
#pragma unroll
        for (int mi = 0; mi < 2; mi++)
#pragma unroll
            for (int c = 0; c < 4; c++)
                acc[mi][0] = __builtin_amdgcn_mfma_f32_32x32x16_bf16(a[mi][c], bfr[c], acc[mi][0], 0, 0, 0);
        __builtin_amdgcn_s_setprio(0);
        SB_BAR();
        // ---- phase 2': B ni=1; stage A(t+2); 8 MFMA; gate; barrier ----
#pragma unroll
        for (int c = 0; c < 4; c++)
            bfr[c] = ldf32(&lds[bf][(c < 2) ? 1 : 3][0],
                           wn * 64 + 32 + l31, (c & 1) * 32 + lk * 16);
        if (t + 2 < nk) {
            stg(Ab, lda, koff + (t + 2) * 64,      &lds[bf][0][0], wave, lane);
            stg(Ab, lda, koff + (t + 2) * 64 + 32, &lds[bf][2][0], wave, lane);
        }
        __builtin_amdgcn_s_setprio(1);
#pragma unroll
        for (int mi = 0; mi < 2; mi++)
#pragma unroll
            for (int c = 0; c < 4; c++)
                acc[mi][1] = __builtin_amdgcn_mfma_f32_32x32x16_bf16(a[mi][c], bfr[c], acc[mi][1], 0, 0, 0);
        __builtin_amdgcn_s_setprio(0);
        if (t + 1 < nk) {
            if (t + 2 < nk) { asm volatile("s_waitcnt vmcnt(4)"); }
            else            { asm volatile("s_waitcnt vmcnt(0)"); }
        }
        SB_BAR();
    }
    // epilogue: col = n0+wn*64+ni*32+l31 ; row = m0+wm*64+mi*32 + 8*q + 4*lk + j (reg=4q+j)
#pragma unroll
    for (int ni = 0; ni < 2; ni++) {
        int col = n0 + wn * 64 + ni * 32 + l31;
        float bb = 0.f;
        if (EPI != 4) bb = bias[col];
#pragma unroll
        for (int mi = 0; mi < 2; mi++) {
#pragma unroll
            for (int qq = 0; qq < 4; qq++) {
                int row0 = m0 + wm * 64 + mi * 32 + qq * 8 + lk * 4;
                if (VT && col >= 2 * D) {
                    int dv = col - 2 * D;
                    int b_ = row0 >> 10, t_ = row0 & (T - 1);
                    u16x4 pk;
#pragma unroll
                    for (int j = 0; j < 4; j++) pk[j] = f2bf(acc[mi][ni][qq * 4 + j] + bb);
                    *(u16x4*)(vT + ((size_t)(b_ * 16 + (dv >> 6)) * HD + (dv & 63)) * T + t_) = pk;
                } else {
#pragma unroll
                    for (int j = 0; j < 4; j++) {
                        int row = row0 + j;
                        float o = acc[mi][ni][qq * 4 + j] + bb;
                        if (EPI == 1) o = 0.5f * o * (1.f + erff(o * 0.70710678118f));
                        if (EPI == 4) {
                            ((u16*)Cv)[((size_t)blockIdx.z * (B * T) + row) * ldc + col] = f2bf(o);
                        } else {
                            ((u16*)Cv)[(size_t)row * ldc + col] = f2bf(o);
                        }
                    }
                }
            }
        }
    }
}

// ------- 256x256 BK=64 merged 2-phase counted-vmcnt GEMM (8 waves, 32 MFMA/phase) -----
__global__ __launch_bounds__(512, 2) void k_gemm8(
        const u16* __restrict__ A, int lda,
        const u16* __restrict__ Bt, int ldb,
        const float* __restrict__ bias,
        float* __restrict__ C, int ldc, int K) {
    __shared__ u16 lds[2][4][256 * 32];   // [buf][Ak0,Bk0,Ak1,Bk1]
    int gm = gridDim.x, nwg = gm * gridDim.y;
    int orig = blockIdx.y * gm + blockIdx.x;
    int xcd = orig & 7, idx = orig >> 3;
    int q = nwg >> 3, rr = nwg & 7;
    int wg = (xcd < rr ? xcd * (q + 1) : rr * (q + 1) + (xcd - rr) * q) + idx;
    int m0 = (wg % gm) * 256, n0 = (wg / gm) * 256;
    int tid = threadIdx.x, wave = tid >> 6, lane = tid & 63;
    int llo = lane & 15, lhi = lane >> 4;
    int wm = wave >> 2, wn = wave & 3;
    const u16* Ab = A + (size_t)m0 * lda;
    const u16* Bb = Bt + (size_t)n0 * ldb;
    int nk = K >> 6;
    f32x4 acc[8][4] = {};
    stg(Ab, lda, 0,   &lds[0][0][0], wave, lane);
    stg(Bb, ldb, 0,   &lds[0][1][0], wave, lane);
    stg(Ab, lda, 32,  &lds[0][2][0], wave, lane);
    stg(Bb, ldb, 32,  &lds[0][3][0], wave, lane);
    stg(Ab, lda, 64,  &lds[1][0][0], wave, lane);
    stg(Ab, lda, 96,  &lds[1][2][0], wave, lane);
    asm volatile("s_waitcnt vmcnt(4)");
    SB_BAR();
    for (int t = 0; t < nk; ++t) {
        const int bf = t & 1;
        bf16x8 a0[8], a1[8], b0, b1, b2, b3;
#pragma unroll
        for (int mi = 0; mi < 8; mi++) a0[mi] = ldf(&lds[bf][0][0], wm * 128 + mi * 16 + llo, lhi);
#pragma unroll
        for (int mi = 0; mi < 8; mi++) a1[mi] = ldf(&lds[bf][2][0], wm * 128 + mi * 16 + llo, lhi);
        b0 = ldf(&lds[bf][1][0], wn * 64 + llo, lhi);
        b1 = ldf(&lds[bf][1][0], wn * 64 + 16 + llo, lhi);
        b2 = ldf(&lds[bf][3][0], wn * 64 + llo, lhi);
        b3 = ldf(&lds[bf][3][0], wn * 64 + 16 + llo, lhi);
        if (t + 1 < nk) {
            stg(Bb, ldb, (t + 1) * 64,      &lds[bf ^ 1][1][0], wave, lane);
            stg(Bb, ldb, (t + 1) * 64 + 32, &lds[bf ^ 1][3][0], wave, lane);
        }
        __builtin_amdgcn_s_setprio(1);
#pragma unroll
        for (int mi = 0; mi < 8; mi++) {
            acc[mi][0] = __builtin_amdgcn_mfma_f32_16x16x32_bf16(a0[mi], b0, acc[mi][0], 0, 0, 0);
            acc[mi][1] = __builtin_amdgcn_mfma_f32_16x16x32_bf16(a0[mi], b1, acc[mi][1], 0, 0, 0);
        }
#pragma unroll
        for (int mi = 0; mi < 8; mi++) {
            acc[mi][0] = __builtin_amdgcn_mfma_f32_16x16x32_bf16(a1[mi], b2, acc[mi][0], 0, 0, 0);
            acc[mi][1] = __builtin_amdgcn_mfma_f32_16x16x32_bf16(a1[mi], b3, acc[mi][1], 0, 0, 0);
        }
        __builtin_amdgcn_s_setprio(0);
        SB_BAR();
        b0 = ldf(&lds[bf][1][0], wn * 64 + 32 + llo, lhi);
        b1 = ldf(&lds[bf][1][0], wn * 64 + 48 + llo, lhi);
        b2 = ldf(&lds[bf][3][0], wn * 64 + 32 + llo, lhi);
        b3 = ldf(&lds[bf][3][0], wn * 64 + 48 + llo, lhi);
        if (t + 2 < nk) {
            stg(Ab, lda, (t + 2) * 64,      &lds[bf][0][0], wave, lane);
            stg(Ab, lda, (t + 2) * 64 + 32, &lds[bf][2][0], wave, lane);
        }
        __builtin_amdgcn_s_setprio(1);
#pragma unroll
        for (int mi = 0; mi < 8; mi++) {
            acc[mi][2] = __builtin_amdgcn_mfma_f32_16x16x32_bf16(a0[mi], b0, acc[mi][2], 0, 0, 0);
            acc[mi][3] = __builtin_amdgcn_mfma_f32_16x16x32_bf16(a0[mi], b1, acc[mi][3], 0, 0, 0);
        }
#pragma unroll
        for (int mi = 0; mi < 8; mi++) {
            acc[mi][2] = __builtin_amdgcn_mfma_f32_16x16x32_bf16(a1[mi], b2, acc[mi][2], 0, 0, 0);
            acc[mi][3] = __builtin_amdgcn_mfma_f32_16x16x32_bf16(a1[mi], b3, acc[mi][3], 0, 0, 0);
        }
        __builtin_amdgcn_s_setprio(0);
        if (t + 1 < nk) {
            if (t + 2 < nk) { asm volatile("s_waitcnt vmcnt(4)"); }
            else            { asm volatile("s_waitcnt vmcnt(0)"); }
        }
        SB_BAR();
    }
#pragma unroll
    for (int ni = 0; ni < 4; ni++) {
        int col = n0 + wn * 64 + ni * 16 + llo;
        float bb = bias[col];
#pragma unroll
        for (int mi = 0; mi < 8; mi++) {
            int row0 = m0 + wm * 128 + mi * 16 + lhi * 4;
#pragma unroll
            for (int r = 0; r < 4; r++)
                C[(size_t)(row0 + r) * ldc + col] = acc[mi][ni][r] + bb;
        }
    }
}

// ------- fused flash attention (KVBLK=32, defer-max) + prob write + embB-cast --------
template <int PW>
__global__ __launch_bounds__(256) void k_fattn(const u16* __restrict__ qkv,
        const u16* __restrict__ vT, u16* __restrict__ out, float* __restrict__ attnF,
        const float* __restrict__ embf, u16* __restrict__ embB, int castBase) {
    __shared__ u16 plds[4][16 * 40];
    int gid = blockIdx.x, tid = threadIdx.x;
    if (gid >= 512) {
        size_t base = ((size_t)castBase + (gid - 512)) * 16384;
        const f32x4* src = (const f32x4*)(embf + base);
        u16x4* dst = (u16x4*)(embB + base);
#pragma unroll 4
        for (int i = 0; i < 16; i++) {
            f32x4 v = src[i * 256 + tid];
            u16x4 o;
#pragma unroll
            for (int j = 0; j < 4; j++) o[j] = f2bf(v[j]);
            dst[i * 256 + tid] = o;
        }
        return;
    }
    int bh = gid >> 4; int b = bh >> 4, h = bh & 15;
    int wave = tid >> 6, lane = tid & 63;
    int llo = lane & 15, lhi = lane >> 4;
    int i0 = (gid & 15) * 64 + wave * 16;
    const u16* qb = qkv + (size_t)b * T * (3 * D) + h * HD;
    const u16* kb = qb + D;
    const u16* vt = vT + (size_t)bh * HD * T;
    bf16x8 q0 = ld8(qb + (size_t)(i0 + llo) * (3 * D) + lhi * 8);
    bf16x8 q1 = ld8(qb + (size_t)(i0 + llo) * (3 * D) + 32 + lhi * 8);
    int qrow = i0 + llo;
    float m = -3e38f, s = 0.f;
    f32x4 oacc[4] = {};
    u16* pw = &plds[wave][0];
    for (int k0 = 0; k0 < i0 + 16; k0 += 32) {
        f32x4 sc0 = {}, sc1 = {};
        {
            bf16x8 kf0 = ld8(kb + (size_t)(k0 + llo) * (3 * D) + lhi * 8);
            bf16x8 kf1 = ld8(kb + (size_t)(k0 + llo) * (3 * D) + 32 + lhi * 8);
            sc0 = __builtin_amdgcn_mfma_f32_16x16x32_bf16(kf0, q0, sc0, 0, 0, 0);
            sc0 = __builtin_amdgcn_mfma_f32_16x16x32_bf16(kf1, q1, sc0, 0, 0, 0);
        }
        if (k0 + 16 < i0 + 16) {
            bf16x8 kf0 = ld8(kb + (size_t)(k0 + 16 + llo) * (3 * D) + lhi * 8);
            bf16x8 kf1 = ld8(kb + (size_t)(k0 + 16 + llo) * (3 * D) + 32 + lhi * 8);
            sc1 = __builtin_amdgcn_mfma_f32_16x16x32_bf16(kf0, q0, sc1, 0, 0, 0);
            sc1 = __builtin_amdgcn_mfma_f32_16x16x32_bf16(kf1, q1, sc1, 0, 0, 0);
        }
        float vv[8]; float tmx = -3e38f;
#pragma unroll
        for (int hf = 0; hf < 2; hf++)
#pragma unroll
            for (int r = 0; r < 4; r++) {
                int k = k0 + hf * 16 + lhi * 4 + r;
                float x = (hf ? sc1[r] : sc0[r]) * 0.125f;
                float v = (k <= qrow) ? x : -3e38f;
                vv[hf * 4 + r] = v;
                tmx = fmaxf(tmx, v);
            }
        tmx = fmaxf(tmx, __shfl_xor(tmx, 16));
        tmx = fmaxf(tmx, __shfl_xor(tmx, 32));
        bool defer = __all(tmx <= m + 8.f);
        float nm = defer ? m : fmaxf(m, tmx);
        float p[8]; float ps = 0.f;
#pragma unroll
        for (int j = 0; j < 8; j++) { p[j] = __expf(vv[j] - nm); ps += p[j]; }
        ps += __shfl_xor(ps, 16);
        ps += __shfl_xor(ps, 32);
        if (!defer) {
            float scale = __expf(m - nm);
            s = s * scale + ps;
            m = nm;
            float sr[4];
#pragma unroll
            for (int r = 0; r < 4; r++) sr[r] = __shfl(scale, lhi * 4 + r);
#pragma unroll
            for (int n = 0; n < 4; n++)
#pragma unroll
                for (int r = 0; r < 4; r++) oacc[n][r] *= sr[r];
        } else {
            s += ps;
        }
#pragma unroll
        for (int hf = 0; hf < 2; hf++) {
            u16x4 pk;
#pragma unroll
            for (int r = 0; r < 4; r++) pk[r] = f2bf(p[hf * 4 + r]);
            *(u16x4*)(pw + llo * 40 + hf * 16 + lhi * 4) = pk;
        }
        bf16x8 pa = ld8(pw + llo * 40 + lhi * 8);
#pragma unroll
        for (int n = 0; n < 4; n++) {
            bf16x8 vb = ld8(vt + (size_t)(n * 16 + llo) * T + k0 + lhi * 8);
            oacc[n] = __builtin_amdgcn_mfma_f32_16x16x32_bf16(pa, vb, oacc[n], 0, 0, 0);
        }
    }
    float inv = 1.f / s;
    float ir[4];
#pragma unroll
    for (int r = 0; r < 4; r++) ir[r] = __shfl(inv, lhi * 4 + r);
#pragma unroll
    for (int n = 0; n < 4; n++)
#pragma unroll
        for (int r = 0; r < 4; r++) {
            int i = i0 + lhi * 4 + r, c = n * 16 + llo;
            out[(size_t)(b * T + i) * D + h * HD + c] = f2bf(oacc[n][r] * ir[r]);
        }
    if (PW) {
        float* ar = attnF + ((size_t)bh * T + qrow) * T;
        for (int j0 = 0; j0 < T; j0 += 16) {
            f32x4 pv = {};
            if (j0 <= qrow) {
                if (j0 < i0 + 16) {
                    bf16x8 kf0 = ld8(kb + (size_t)(j0 + llo) * (3 * D) + lhi * 8);
                    bf16x8 kf1 = ld8(kb + (size_t)(j0 + llo) * (3 * D) + 32 + lhi * 8);
                    f32x4 sc = {};
                    sc = __builtin_amdgcn_mfma_f32_16x16x32_bf16(kf0, q0, sc, 0, 0, 0);
                    sc = __builtin_amdgcn_mfma_f32_16x16x32_bf16(kf1, q1, sc, 0, 0, 0);
#pragma unroll
                    for (int r = 0; r < 4; r++) {
                        int j = j0 + lhi * 4 + r;
                        pv[r] = (j <= qrow) ? __expf(sc[r] * 0.125f - m) * inv : 0.f;
                    }
                }
            }
            *(f32x4*)(ar + j0 + lhi * 4) = pv;
        }
    }
}

extern "C" void kernel_launch(void* const* d_in, const int* in_sizes, int n_in,
                              void* d_out, int out_size, void* d_ws, size_t ws_size,
                              hipStream_t stream) {
    const int*   tok   = (const int*)d_in[0];
    const float* emb   = (const float*)d_in[2];
    const float* pe    = (const float*)d_in[3];
    const float* ln1g  = (const float*)d_in[4];
    const float* ln1b  = (const float*)d_in[5];
    const float* Wqkv  = (const float*)d_in[6];
    const float* bqkv  = (const float*)d_in[7];
    const float* Wproj = (const float*)d_in[8];
    const float* bproj = (const float*)d_in[9];
    const float* ln2g  = (const float*)d_in[10];
    const float* ln2b  = (const float*)d_in[11];
    const float* W1    = (const float*)d_in[12];
    const float* b1    = (const float*)d_in[13];
    const float* W2    = (const float*)d_in[14];
    const float* b2    = (const float*)d_in[15];
    const float* lnfg  = (const float*)d_in[16];
    const float* lnfb  = (const float*)d_in[17];
    const float* outb  = (const float*)d_in[18];

    float* logits  = (float*)d_out;
    float* attnF   = logits + (size_t)B * T * V;

    char* w = (char*)d_ws;
    float* x    = (float*)w;  w += (size_t)B * T * D * 4;           // 8.39 MB
    u16* lnout  = (u16*)w;    w += (size_t)B * T * D * 2;           // 4.19 MB
    u16* qkv    = (u16*)w;    w += (size_t)B * T * 3 * D * 2;       // 12.58 MB
    u16* vT     = (u16*)w;    w += (size_t)B * H * HD * T * 2;      // 4.19 MB
    u16* aout   = (u16*)w;    w += (size_t)B * T * D * 2;           // 4.19 MB
    u16* hmid   = (u16*)w;    w += (size_t)B * T * F * 2;           // 16.78 MB
    u16* WTL    = (u16*)w;    w += (size_t)(5 * D * D + 2 * D * F) * 2; // 25.17 MB
    u16* pp     = (u16*)w;    w += (size_t)4 * B * T * D * 2;       // 16.78 MB (bf16 partials)
    u16* embB   = (u16*)w;    w += (size_t)V * D * 2;               // 65.54 MB

    dim3 blk(256);
    const int CG = 3072;        // castT4 strips
    const int CC = 500;         // embB cast chunks per fattn dispatch
    k_emblnT<<<dim3(B * T + CG), blk, 0, stream>>>(tok, emb, pe, ln1g, ln1b, x, lnout,
        Wqkv, Wproj, W1, W2, WTL);

    for (int l = 0; l < L; l++) {
        k_gemm4<0, true><<<dim3(B * T / 128, 3 * D / 128), blk, 0, stream>>>(
            lnout, D, WTL, D, bqkv + l * 3 * D, qkv, 3 * D, D, vT);
        if (l == L - 1)
            k_fattn<1><<<dim3(512 + CC), blk, 0, stream>>>(qkv, vT, aout, attnF,
                emb, embB, l * CC);
        else
            k_fattn<0><<<dim3(512 + CC), blk, 0, stream>>>(qkv, vT, aout, attnF,
                emb, embB, l * CC);
        k_gemm4<4, false><<<dim3(B * T / 128, D / 128, 4), blk, 0, stream>>>(
            aout, D, WTL + (size_t)3 * D * D, D, nullptr, pp, D, D / 4, nullptr);
        k_redlnT<4, false, true><<<dim3(B * T), blk, 0, stream>>>(pp, bproj + l * D, x,
            ln2g + l * D, ln2b + l * D, lnout, nullptr, nullptr, nullptr, nullptr, nullptr);
        k_gemm4<1, false><<<dim3(B * T / 128, F / 128), blk, 0, stream>>>(
            lnout, D, WTL + (size_t)4 * D * D, D, b1 + l * F, hmid, F, D, nullptr);
        k_gemm4<4, false><<<dim3(B * T / 128, D / 128, 4), blk, 0, stream>>>(
            hmid, F, WTL + (size_t)4 * D * D + D * F, F, nullptr, pp, D, F / 4, nullptr);
        if (l < L - 1) {
            k_redlnT<4, true, true><<<dim3(B * T + CG), blk, 0, stream>>>(pp, b2 + l * D, x,
                ln1g + (l + 1) * D, ln1b + (l + 1) * D, lnout,
                Wqkv + (size_t)(l + 1) * D * 3 * D, Wproj + (size_t)(l + 1) * D * D,
                W1 + (size_t)(l + 1) * D * F, W2 + (size_t)(l + 1) * F * D, WTL);
        } else {
            k_redlnT<4, false, false><<<dim3(B * T), blk, 0, stream>>>(pp, b2 + l * D, x,
                lnfg, lnfb, lnout, nullptr, nullptr, nullptr, nullptr, nullptr);
        }
    }
    k_gemm8<<<dim3(B * T / 256, V / 256), dim3(512), 0, stream>>>(
        lnout, D, embB, D, outb, logits, V, D);
}

// Round 17
// 933.141 us; speedup vs baseline: 1.0257x; 1.0257x over previous
//
#include <hip/hip_runtime.h>
#include <cstdint>

#define DEV static __device__ __forceinline__

typedef unsigned short u16;
typedef __bf16 bf16x8 __attribute__((ext_vector_type(8)));
typedef float f32x4 __attribute__((ext_vector_type(4)));
typedef unsigned short u16x4 __attribute__((ext_vector_type(4)));

constexpr int V = 32000, D = 1024, H = 16, L = 4, F = 4096, T = 1024, B = 2;
constexpr int HD = 64;

DEV u16 f2bf(float f) {
    union { float f; uint32_t i; } c; c.f = f;
    uint32_t x = c.i;
    return (u16)((x + 0x7fffu + ((x >> 16) & 1u)) >> 16);
}
DEV float bf2f(u16 u) {
    union { uint32_t i; float f; } c; c.i = ((uint32_t)u) << 16; return c.f;
}
DEV bf16x8 ld8(const u16* p) { return *reinterpret_cast<const bf16x8*>(p); }

DEV void gl16(const void* g, void* l) {
    __builtin_amdgcn_global_load_lds((const __attribute__((address_space(1))) void*)g,
                                     (__attribute__((address_space(3))) void*)l, 16, 0, 0);
}

// ---- batched transpose+cast device body: one 32x128 strip per block ----
DEV void castT4_dev(int t, int x, int y, u16 (*tl)[33],
        const float* __restrict__ Wqkv, const float* __restrict__ Wproj,
        const float* __restrict__ W1, const float* __restrict__ W2,
        u16* __restrict__ wt) {
    const float* src; u16* dst; int Rr, Cc;
    if (t < 768)       { src = Wqkv;  dst = wt;                       Rr = D; Cc = 3 * D; }
    else if (t < 1024) { src = Wproj; dst = wt + 3 * D * D;           Rr = D; Cc = D; t -= 768; }
    else if (t < 2048) { src = W1;    dst = wt + 4 * D * D;           Rr = D; Cc = F; t -= 1024; }
    else               { src = W2;    dst = wt + 4 * D * D + D * F;   Rr = F; Cc = D; t -= 2048; }
    int colStrips = Cc >> 7;
    int r0 = (t / colStrips) * 32;
    int c0 = (t % colStrips) * 128;
    for (int i = 0; i < 4; i++) {
        int cc = c0 + i * 32;
        __syncthreads();
#pragma unroll
        for (int j = 0; j < 4; j++)
            tl[y + j * 8][x] = f2bf(src[(size_t)(r0 + y + j * 8) * Cc + cc + x]);
        __syncthreads();
#pragma unroll
        for (int j = 0; j < 4; j++)
            dst[(size_t)(cc + y + j * 8) * Rr + r0 + x] = tl[x][y + j * 8];
    }
}

// ---------------- embedding + ln1(layer0), merged with castT4(layer0) ----------------
__global__ __launch_bounds__(256) void k_emblnT(const int* __restrict__ tok,
        const float* __restrict__ emb, const float* __restrict__ pe,
        const float* __restrict__ g, const float* __restrict__ b,
        float* __restrict__ x, u16* __restrict__ out,
        const float* __restrict__ Wqkv, const float* __restrict__ Wproj,
        const float* __restrict__ W1, const float* __restrict__ W2,
        u16* __restrict__ wt) {
    __shared__ u16 tl[32][33];
    __shared__ float ps[4], ps2[4];
    int row = blockIdx.x, tid = threadIdx.x;
    if (row >= B * T) {
        castT4_dev(row - B * T, tid & 31, tid >> 5, tl, Wqkv, Wproj, W1, W2, wt);
        return;
    }
    int t = row & (T - 1);
    int vv = tok[row];
    f32x4 v = ((const f32x4*)(emb + (size_t)vv * D))[tid] + ((const f32x4*)(pe + (size_t)t * D))[tid];
    ((f32x4*)(x + (size_t)row * D))[tid] = v;
    float s = v[0] + v[1] + v[2] + v[3];
    float s2 = v[0]*v[0] + v[1]*v[1] + v[2]*v[2] + v[3]*v[3];
#pragma unroll
    for (int m = 1; m < 64; m <<= 1) { s += __shfl_xor(s, m); s2 += __shfl_xor(s2, m); }
    int wave = tid >> 6;
    if ((tid & 63) == 0) { ps[wave] = s; ps2[wave] = s2; }
    __syncthreads();
    s = ps[0] + ps[1] + ps[2] + ps[3];
    s2 = ps2[0] + ps2[1] + ps2[2] + ps2[3];
    float mean = s * (1.f / D);
    float var = s2 * (1.f / D) - mean * mean;
    float r = rsqrtf(var + 1e-5f);
    f32x4 gg = ((const f32x4*)g)[tid];
    f32x4 bb = ((const f32x4*)b)[tid];
    u16x4 o;
#pragma unroll
    for (int j = 0; j < 4; j++) o[j] = f2bf((v[j] - mean) * r * gg[j] + bb[j]);
    ((u16x4*)(out + (size_t)row * D))[tid] = o;
}

// ------- splitK reduce (bf16 partials) + bias + residual + LayerNorm (+castT4) -------
// WX: write updated residual back to x (skip for the final layer where x is dead).
template <int S, bool DOCAST, bool WX>
__global__ __launch_bounds__(256) void k_redlnT(const u16* __restrict__ pp,
        const float* __restrict__ bias, float* __restrict__ x,
        const float* __restrict__ g, const float* __restrict__ b,
        u16* __restrict__ out,
        const float* __restrict__ Wqkv, const float* __restrict__ Wproj,
        const float* __restrict__ W1, const float* __restrict__ W2,
        u16* __restrict__ wt) {
    __shared__ u16 tl[32][33];
    __shared__ float ps[4], ps2[4];
    int row = blockIdx.x, tid = threadIdx.x;
    if (DOCAST && row >= B * T) {
        castT4_dev(row - B * T, tid & 31, tid >> 5, tl, Wqkv, Wproj, W1, W2, wt);
        return;
    }
    f32x4 v = ((const f32x4*)(x + (size_t)row * D))[tid];
#pragma unroll
    for (int s = 0; s < S; s++) {
        u16x4 pk = ((const u16x4*)(pp + ((size_t)s * (B * T) + row) * D))[tid];
#pragma unroll
        for (int j = 0; j < 4; j++) v[j] += bf2f(pk[j]);
    }
    v += ((const f32x4*)bias)[tid];
    if (WX) ((f32x4*)(x + (size_t)row * D))[tid] = v;
    float s = v[0] + v[1] + v[2] + v[3];
    float s2 = v[0]*v[0] + v[1]*v[1] + v[2]*v[2] + v[3]*v[3];
#pragma unroll
    for (int m = 1; m < 64; m <<= 1) { s += __shfl_xor(s, m); s2 += __shfl_xor(s2, m); }
    int wave = tid >> 6;
    if ((tid & 63) == 0) { ps[wave] = s; ps2[wave] = s2; }
    __syncthreads();
    s = ps[0] + ps[1] + ps[2] + ps[3];
    s2 = ps2[0] + ps2[1] + ps2[2] + ps2[3];
    float mean = s * (1.f / D);
    float var = s2 * (1.f / D) - mean * mean;
    float r = rsqrtf(var + 1e-5f);
    f32x4 gg = ((const f32x4*)g)[tid];
    f32x4 bb = ((const f32x4*)b)[tid];
    u16x4 o;
#pragma unroll
    for (int j = 0; j < 4; j++) o[j] = f2bf((v[j] - mean) * r * gg[j] + bb[j]);
    ((u16x4*)(out + (size_t)row * D))[tid] = o;
}

// ---- shared pipeline helpers (swizzle is a size-independent involution) ----
DEV bf16x8 ldf(const u16* half, int row, int lhi) {
    int lb = row * 64 + lhi * 16;
    lb ^= ((lb >> 9) & 1) << 5;
    return *(const bf16x8*)((const char*)half + lb);
}
DEV void stg(const u16* gb, int ld, int kc, u16* dstBase, int wave, int lane) {
#pragma unroll
    for (int i = 0; i < 2; i++) {
        int p = (wave * 2 + i) * 64 + lane;
        int l = p ^ (((p >> 5) & 1) << 1);
        gl16(gb + (size_t)(l >> 2) * ld + kc + (l & 3) * 8, dstBase + (wave * 2 + i) * 512);
    }
}
#define SB_BAR() do { __builtin_amdgcn_sched_barrier(0); __builtin_amdgcn_s_barrier(); } while (0)

// ------- 128x128 BK=64 merged 2-phase counted-vmcnt GEMM (4 waves, 16 MFMA/phase) -----
template <int EPI, bool VT>
__global__ __launch_bounds__(256, 2) void k_gemm4(
        const u16* __restrict__ A, int lda,
        const u16* __restrict__ Bt, int ldb,
        const float* __restrict__ bias,
        void* __restrict__ Cv, int ldc, int K, u16* __restrict__ vT) {
    __shared__ u16 lds[2][4][128 * 32];   // [buf][Ak0,Bk0,Ak1,Bk1]
    int gm = gridDim.x, nwg = gm * gridDim.y;
    int orig = blockIdx.y * gm + blockIdx.x;
    int xcd = orig & 7, idx = orig >> 3;
    int q = nwg >> 3, rr = nwg & 7;
    int wg = (xcd < rr ? xcd * (q + 1) : rr * (q + 1) + (xcd - rr) * q) + idx;
    int m0 = (wg % gm) * 128, n0 = (wg / gm) * 128;
    int koff = (EPI == 4) ? blockIdx.z * K : 0;
    int tid = threadIdx.x, wave = tid >> 6, lane = tid & 63;
    int llo = lane & 15, lhi = lane >> 4;
    int wm = wave >> 1, wn = wave & 1;
    const u16* Ab = A + (size_t)m0 * lda;
    const u16* Bb = Bt + (size_t)n0 * ldb;
    int nk = K >> 6;
    f32x4 acc[4][4] = {};
    stg(Ab, lda, koff + 0,   &lds[0][0][0], wave, lane);
    stg(Bb, ldb, koff + 0,   &lds[0][1][0], wave, lane);
    stg(Ab, lda, koff + 32,  &lds[0][2][0], wave, lane);
    stg(Bb, ldb, koff + 32,  &lds[0][3][0], wave, lane);
    stg(Ab, lda, koff + 64,  &lds[1][0][0], wave, lane);
    stg(Ab, lda, koff + 96,  &lds[1][2][0], wave, lane);
    asm volatile("s_waitcnt vmcnt(4)");
    SB_BAR();
    for (int t = 0; t < nk; ++t) {
        const int bf = t & 1;
        bf16x8 a0[4], a1[4], b0, b1, b2, b3;
#pragma unroll
        for (int mi = 0; mi < 4; mi++) a0[mi] = ldf(&lds[bf][0][0], wm * 64 + mi * 16 + llo, lhi);
#pragma unroll
        for (int mi = 0; mi < 4; mi++) a1[mi] = ldf(&lds[bf][2][0], wm * 64 + mi * 16 + llo, lhi);
        b0 = ldf(&lds[bf][1][0], wn * 64 + llo, lhi);
        b1 = ldf(&lds[bf][1][0], wn * 64 + 16 + llo, lhi);
        b2 = ldf(&lds[bf][3][0], wn * 64 + llo, lhi);
        b3 = ldf(&lds[bf][3][0], wn * 64 + 16 + llo, lhi);
        if (t + 1 < nk) {
            stg(Bb, ldb, koff + (t + 1) * 64,      &lds[bf ^ 1][1][0], wave, lane);
            stg(Bb, ldb, koff + (t + 1) * 64 + 32, &lds[bf ^ 1][3][0], wave, lane);
        }
        __builtin_amdgcn_s_setprio(1);
#pragma unroll
        for (int mi = 0; mi < 4; mi++) {
            acc[mi][0] = __builtin_amdgcn_mfma_f32_16x16x32_bf16(a0[mi], b0, acc[mi][0], 0, 0, 0);
            acc[mi][1] = __builtin_amdgcn_mfma_f32_16x16x32_bf16(a0[mi], b1, acc[mi][1], 0, 0, 0);
        }
#pragma unroll
        for (int mi = 0; mi < 4; mi++) {
            acc[mi][0] = __builtin_amdgcn_mfma_f32_16x16x32_bf16(a1[mi], b2, acc[mi][0], 0, 0, 0);
            acc[mi][1] = __builtin_amdgcn_mfma_f32_16x16x32_bf16(a1[mi], b3, acc[mi][1], 0, 0, 0);
        }
        __builtin_amdgcn_s_setprio(0);
        SB_BAR();
        b0 = ldf(&lds[bf][1][0], wn * 64 + 32 + llo, lhi);
        b1 = ldf(&lds[bf][1][0], wn * 64 + 48 + llo, lhi);
        b2 = ldf(&lds[bf][3][0], wn * 64 + 32 + llo, lhi);
        b3 = ldf(&lds[bf][3][0], wn * 64 + 48 + llo, lhi);
        if (t + 2 < nk) {
            stg(Ab, lda, koff + (t + 2) * 64,      &lds[bf][0][0], wave, lane);
            stg(Ab, lda, koff + (t + 2) * 64 + 32, &lds[bf][2][0], wave, lane);
        }
        __builtin_amdgcn_s_setprio(1);
#pragma unroll
        for (int mi = 0; mi < 4; mi++) {
            acc[mi][2] = __builtin_amdgcn_mfma_f32_16x16x32_bf16(a0[mi], b0, acc[mi][2], 0, 0, 0);
            acc[mi][3] = __builtin_amdgcn_mfma_f32_16x16x32_bf16(a0[mi], b1, acc[mi][3], 0, 0, 0);
        }
#pragma unroll
        for (int mi = 0; mi < 4; mi++) {
            acc[mi][2] = __builtin_amdgcn_mfma_f32_16x16x32_bf16(a1[mi], b2, acc[mi][2], 0, 0, 0);
            acc[mi][3] = __builtin_amdgcn_mfma_f32_16x16x32_bf16(a1[mi], b3, acc[mi][3], 0, 0, 0);
        }
        __builtin_amdgcn_s_setprio(0);
        if (t + 1 < nk) {
            if (t + 2 < nk) { asm volatile("s_waitcnt vmcnt(4)"); }
            else            { asm volatile("s_waitcnt vmcnt(0)"); }
        }
        SB_BAR();
    }
#pragma unroll
    for (int ni = 0; ni < 4; ni++) {
        int col = n0 + wn * 64 + ni * 16 + llo;
        float bb = 0.f;
        if (EPI != 4) bb = bias[col];
#pragma unroll
        for (int mi = 0; mi < 4; mi++) {
            int row0 = m0 + wm * 64 + mi * 16 + lhi * 4;
            if (VT && col >= 2 * D) {
                int dv = col - 2 * D;
                int b_ = row0 >> 10, t_ = row0 & (T - 1);
                u16x4 pk;
#pragma unroll
                for (int r = 0; r < 4; r++) pk[r] = f2bf(acc[mi][ni][r] + bb);
                *(u16x4*)(vT + ((size_t)(b_ * 16 + (dv >> 6)) * HD + (dv & 63)) * T + t_) = pk;
            } else {
#pragma unroll
                for (int r = 0; r < 4; r++) {
                    int row = row0 + r;
                    float o = acc[mi][ni][r] + bb;
                    if (EPI == 1) o = 0.5f * o * (1.f + erff(o * 0.70710678118f));
                    if (EPI == 4) {
                        ((u16*)Cv)[((size_t)blockIdx.z * (B * T) + row) * ldc + col] = f2bf(o);
                    } else {
                        ((u16*)Cv)[(size_t)row * ldc + col] = f2bf(o);
                    }
                }
            }
        }
    }
}

// ------- 256x256 BK=64 merged 2-phase counted-vmcnt GEMM (8 waves, 32 MFMA/phase) -----
__global__ __launch_bounds__(512, 2) void k_gemm8(
        const u16* __restrict__ A, int lda,
        const u16* __restrict__ Bt, int ldb,
        const float* __restrict__ bias,
        float* __restrict__ C, int ldc, int K) {
    __shared__ u16 lds[2][4][256 * 32];   // [buf][Ak0,Bk0,Ak1,Bk1]
    int gm = gridDim.x, nwg = gm * gridDim.y;
    int orig = blockIdx.y * gm + blockIdx.x;
    int xcd = orig & 7, idx = orig >> 3;
    int q = nwg >> 3, rr = nwg & 7;
    int wg = (xcd < rr ? xcd * (q + 1) : rr * (q + 1) + (xcd - rr) * q) + idx;
    int m0 = (wg % gm) * 256, n0 = (wg / gm) * 256;
    int tid = threadIdx.x, wave = tid >> 6, lane = tid & 63;
    int llo = lane & 15, lhi = lane >> 4;
    int wm = wave >> 2, wn = wave & 3;
    const u16* Ab = A + (size_t)m0 * lda;
    const u16* Bb = Bt + (size_t)n0 * ldb;
    int nk = K >> 6;
    f32x4 acc[8][4] = {};
    stg(Ab, lda, 0,   &lds[0][0][0], wave, lane);
    stg(Bb, ldb, 0,   &lds[0][1][0], wave, lane);
    stg(Ab, lda, 32,  &lds[0][2][0], wave, lane);
    stg(Bb, ldb, 32,  &lds[0][3][0], wave, lane);
    stg(Ab, lda, 64,  &lds[1][0][0], wave, lane);
    stg(Ab, lda, 96,  &lds[1][2][0], wave, lane);
    asm volatile("s_waitcnt vmcnt(4)");
    SB_BAR();
    for (int t = 0; t < nk; ++t) {
        const int bf = t & 1;
        bf16x8 a0[8], a1[8], b0, b1, b2, b3;
#pragma unroll
        for (int mi = 0; mi < 8; mi++) a0[mi] = ldf(&lds[bf][0][0], wm * 128 + mi * 16 + llo, lhi);
#pragma unroll
        for (int mi = 0; mi < 8; mi++) a1[mi] = ldf(&lds[bf][2][0], wm * 128 + mi * 16 + llo, lhi);
        b0 = ldf(&lds[bf][1][0], wn * 64 + llo, lhi);
        b1 = ldf(&lds[bf][1][0], wn * 64 + 16 + llo, lhi);
        b2 = ldf(&lds[bf][3][0], wn * 64 + llo, lhi);
        b3 = ldf(&lds[bf][3][0], wn * 64 + 16 + llo, lhi);
        if (t + 1 < nk) {
            stg(Bb, ldb, (t + 1) * 64,      &lds[bf ^ 1][1][0], wave, lane);
            stg(Bb, ldb, (t + 1) * 64 + 32, &lds[bf ^ 1][3][0], wave, lane);
        }
        __builtin_amdgcn_s_setprio(1);
#pragma unroll
        for (int mi = 0; mi < 8; mi++) {
            acc[mi][0] = __builtin_amdgcn_mfma_f32_16x16x32_bf16(a0[mi], b0, acc[mi][0], 0, 0, 0);
            acc[mi][1] = __builtin_amdgcn_mfma_f32_16x16x32_bf16(a0[mi], b1, acc[mi][1], 0, 0, 0);
        }
#pragma unroll
        for (int mi = 0; mi < 8; mi++) {
            acc[mi][0] = __builtin_amdgcn_mfma_f32_16x16x32_bf16(a1[mi], b2, acc[mi][0], 0, 0, 0);
            acc[mi][1] = __builtin_amdgcn_mfma_f32_16x16x32_bf16(a1[mi], b3, acc[mi][1], 0, 0, 0);
        }
        __builtin_amdgcn_s_setprio(0);
        SB_BAR();
        b0 = ldf(&lds[bf][1][0], wn * 64 + 32 + llo, lhi);
        b1 = ldf(&lds[bf][1][0], wn * 64 + 48 + llo, lhi);
        b2 = ldf(&lds[bf][3][0], wn * 64 + 32 + llo, lhi);
        b3 = ldf(&lds[bf][3][0], wn * 64 + 48 + llo, lhi);
        if (t + 2 < nk) {
            stg(Ab, lda, (t + 2) * 64,      &lds[bf][0][0], wave, lane);
            stg(Ab, lda, (t + 2) * 64 + 32, &lds[bf][2][0], wave, lane);
        }
        __builtin_amdgcn_s_setprio(1);
#pragma unroll
        for (int mi = 0; mi < 8; mi++) {
            acc[mi][2] = __builtin_amdgcn_mfma_f32_16x16x32_bf16(a0[mi], b0, acc[mi][2], 0, 0, 0);
            acc[mi][3] = __builtin_amdgcn_mfma_f32_16x16x32_bf16(a0[mi], b1, acc[mi][3], 0, 0, 0);
        }
#pragma unroll
        for (int mi = 0; mi < 8; mi++) {
            acc[mi][2] = __builtin_amdgcn_mfma_f32_16x16x32_bf16(a1[mi], b2, acc[mi][2], 0, 0, 0);
            acc[mi][3] = __builtin_amdgcn_mfma_f32_16x16x32_bf16(a1[mi], b3, acc[mi][3], 0, 0, 0);
        }
        __builtin_amdgcn_s_setprio(0);
        if (t + 1 < nk) {
            if (t + 2 < nk) { asm volatile("s_waitcnt vmcnt(4)"); }
            else            { asm volatile("s_waitcnt vmcnt(0)"); }
        }
        SB_BAR();
    }
#pragma unroll
    for (int ni = 0; ni < 4; ni++) {
        int col = n0 + wn * 64 + ni * 16 + llo;
        float bb = bias[col];
#pragma unroll
        for (int mi = 0; mi < 8; mi++) {
            int row0 = m0 + wm * 128 + mi * 16 + lhi * 4;
#pragma unroll
            for (int r = 0; r < 4; r++)
                C[(size_t)(row0 + r) * ldc + col] = acc[mi][ni][r] + bb;
        }
    }
}

// ------- fused flash attention (KVBLK=32, defer-max) + prob write + embB-cast --------
template <int PW>
__global__ __launch_bounds__(256) void k_fattn(const u16* __restrict__ qkv,
        const u16* __restrict__ vT, u16* __restrict__ out, float* __restrict__ attnF,
        const float* __restrict__ embf, u16* __restrict__ embB, int castBase) {
    __shared__ u16 plds[4][16 * 40];
    int gid = blockIdx.x, tid = threadIdx.x;
    if (gid >= 512) {
        size_t base = ((size_t)castBase + (gid - 512)) * 16384;
        const f32x4* src = (const f32x4*)(embf + base);
        u16x4* dst = (u16x4*)(embB + base);
#pragma unroll 4
        for (int i = 0; i < 16; i++) {
            f32x4 v = src[i * 256 + tid];
            u16x4 o;
#pragma unroll
            for (int j = 0; j < 4; j++) o[j] = f2bf(v[j]);
            dst[i * 256 + tid] = o;
        }
        return;
    }
    int bh = gid >> 4; int b = bh >> 4, h = bh & 15;
    int wave = tid >> 6, lane = tid & 63;
    int llo = lane & 15, lhi = lane >> 4;
    int i0 = (gid & 15) * 64 + wave * 16;
    const u16* qb = qkv + (size_t)b * T * (3 * D) + h * HD;
    const u16* kb = qb + D;
    const u16* vt = vT + (size_t)bh * HD * T;
    bf16x8 q0 = ld8(qb + (size_t)(i0 + llo) * (3 * D) + lhi * 8);
    bf16x8 q1 = ld8(qb + (size_t)(i0 + llo) * (3 * D) + 32 + lhi * 8);
    int qrow = i0 + llo;
    float m = -3e38f, s = 0.f;
    f32x4 oacc[4] = {};
    u16* pw = &plds[wave][0];
    for (int k0 = 0; k0 < i0 + 16; k0 += 32) {
        f32x4 sc0 = {}, sc1 = {};
        {
            bf16x8 kf0 = ld8(kb + (size_t)(k0 + llo) * (3 * D) + lhi * 8);
            bf16x8 kf1 = ld8(kb + (size_t)(k0 + llo) * (3 * D) + 32 + lhi * 8);
            sc0 = __builtin_amdgcn_mfma_f32_16x16x32_bf16(kf0, q0, sc0, 0, 0, 0);
            sc0 = __builtin_amdgcn_mfma_f32_16x16x32_bf16(kf1, q1, sc0, 0, 0, 0);
        }
        if (k0 + 16 < i0 + 16) {
            bf16x8 kf0 = ld8(kb + (size_t)(k0 + 16 + llo) * (3 * D) + lhi * 8);
            bf16x8 kf1 = ld8(kb + (size_t)(k0 + 16 + llo) * (3 * D) + 32 + lhi * 8);
            sc1 = __builtin_amdgcn_mfma_f32_16x16x32_bf16(kf0, q0, sc1, 0, 0, 0);
            sc1 = __builtin_amdgcn_mfma_f32_16x16x32_bf16(kf1, q1, sc1, 0, 0, 0);
        }
        float vv[8]; float tmx = -3e38f;
#pragma unroll
        for (int hf = 0; hf < 2; hf++)
#pragma unroll
            for (int r = 0; r < 4; r++) {
                int k = k0 + hf * 16 + lhi * 4 + r;
                float x = (hf ? sc1[r] : sc0[r]) * 0.125f;
                float v = (k <= qrow) ? x : -3e38f;
                vv[hf * 4 + r] = v;
                tmx = fmaxf(tmx, v);
            }
        tmx = fmaxf(tmx, __shfl_xor(tmx, 16));
        tmx = fmaxf(tmx, __shfl_xor(tmx, 32));
        bool defer = __all(tmx <= m + 8.f);
        float nm = defer ? m : fmaxf(m, tmx);
        float p[8]; float ps = 0.f;
#pragma unroll
        for (int j = 0; j < 8; j++) { p[j] = __expf(vv[j] - nm); ps += p[j]; }
        ps += __shfl_xor(ps, 16);
        ps += __shfl_xor(ps, 32);
        if (!defer) {
            float scale = __expf(m - nm);
            s = s * scale + ps;
            m = nm;
            float sr[4];
#pragma unroll
            for (int r = 0; r < 4; r++) sr[r] = __shfl(scale, lhi * 4 + r);
#pragma unroll
            for (int n = 0; n < 4; n++)
#pragma unroll
                for (int r = 0; r < 4; r++) oacc[n][r] *= sr[r];
        } else {
            s += ps;
        }
#pragma unroll
        for (int hf = 0; hf < 2; hf++) {
            u16x4 pk;
#pragma unroll
            for (int r = 0; r < 4; r++) pk[r] = f2bf(p[hf * 4 + r]);
            *(u16x4*)(pw + llo * 40 + hf * 16 + lhi * 4) = pk;
        }
        bf16x8 pa = ld8(pw + llo * 40 + lhi * 8);
#pragma unroll
        for (int n = 0; n < 4; n++) {
            bf16x8 vb = ld8(vt + (size_t)(n * 16 + llo) * T + k0 + lhi * 8);
            oacc[n] = __builtin_amdgcn_mfma_f32_16x16x32_bf16(pa, vb, oacc[n], 0, 0, 0);
        }
    }
    float inv = 1.f / s;
    float ir[4];
#pragma unroll
    for (int r = 0; r < 4; r++) ir[r] = __shfl(inv, lhi * 4 + r);
#pragma unroll
    for (int n = 0; n < 4; n++)
#pragma unroll
        for (int r = 0; r < 4; r++) {
            int i = i0 + lhi * 4 + r, c = n * 16 + llo;
            out[(size_t)(b * T + i) * D + h * HD + c] = f2bf(oacc[n][r] * ir[r]);
        }
    if (PW) {
        float* ar = attnF + ((size_t)bh * T + qrow) * T;
        for (int j0 = 0; j0 < T; j0 += 16) {
            f32x4 pv = {};
            if (j0 <= qrow) {
                if (j0 < i0 + 16) {
                    bf16x8 kf0 = ld8(kb + (size_t)(j0 + llo) * (3 * D) + lhi * 8);
                    bf16x8 kf1 = ld8(kb + (size_t)(j0 + llo) * (3 * D) + 32 + lhi * 8);
                    f32x4 sc = {};
                    sc = __builtin_amdgcn_mfma_f32_16x16x32_bf16(kf0, q0, sc, 0, 0, 0);
                    sc = __builtin_amdgcn_mfma_f32_16x16x32_bf16(kf1, q1, sc, 0, 0, 0);
#pragma unroll
                    for (int r = 0; r < 4; r++) {
                        int j = j0 + lhi * 4 + r;
                        pv[r] = (j <= qrow) ? __expf(sc[r] * 0.125f - m) * inv : 0.f;
                    }
                }
            }
            *(f32x4*)(ar + j0 + lhi * 4) = pv;
        }
    }
}

extern "C" void kernel_launch(void* const* d_in, const int* in_sizes, int n_in,
                              void* d_out, int out_size, void* d_ws, size_t ws_size,
                              hipStream_t stream) {
    const int*   tok   = (const int*)d_in[0];
    const float* emb   = (const float*)d_in[2];
    const float* pe    = (const float*)d_in[3];
    const float* ln1g  = (const float*)d_in[4];
    const float* ln1b  = (const float*)d_in[5];
    const float* Wqkv  = (const float*)d_in[6];
    const float* bqkv  = (const float*)d_in[7];
    const float* Wproj = (const float*)d_in[8];
    const float* bproj = (const float*)d_in[9];
    const float* ln2g  = (const float*)d_in[10];
    const float* ln2b  = (const float*)d_in[11];
    const float* W1    = (const float*)d_in[12];
    const float* b1    = (const float*)d_in[13];
    const float* W2    = (const float*)d_in[14];
    const float* b2    = (const float*)d_in[15];
    const float* lnfg  = (const float*)d_in[16];
    const float* lnfb  = (const float*)d_in[17];
    const float* outb  = (const float*)d_in[18];

    float* logits  = (float*)d_out;
    float* attnF   = logits + (size_t)B * T * V;

    char* w = (char*)d_ws;
    float* x    = (float*)w;  w += (size_t)B * T * D * 4;           // 8.39 MB
    u16* lnout  = (u16*)w;    w += (size_t)B * T * D * 2;           // 4.19 MB
    u16* qkv    = (u16*)w;    w += (size_t)B * T * 3 * D * 2;       // 12.58 MB
    u16* vT     = (u16*)w;    w += (size_t)B * H * HD * T * 2;      // 4.19 MB
    u16* aout   = (u16*)w;    w += (size_t)B * T * D * 2;           // 4.19 MB
    u16* hmid   = (u16*)w;    w += (size_t)B * T * F * 2;           // 16.78 MB
    u16* WTL    = (u16*)w;    w += (size_t)(5 * D * D + 2 * D * F) * 2; // 25.17 MB
    u16* pp     = (u16*)w;    w += (size_t)4 * B * T * D * 2;       // 16.78 MB (bf16 partials)
    u16* embB   = (u16*)w;    w += (size_t)V * D * 2;               // 65.54 MB

    dim3 blk(256);
    const int CG = 3072;        // castT4 strips
    const int CC = 500;         // embB cast chunks per fattn dispatch
    k_emblnT<<<dim3(B * T + CG), blk, 0, stream>>>(tok, emb, pe, ln1g, ln1b, x, lnout,
        Wqkv, Wproj, W1, W2, WTL);

    for (int l = 0; l < L; l++) {
        k_gemm4<0, true><<<dim3(B * T / 128, 3 * D / 128), blk, 0, stream>>>(
            lnout, D, WTL, D, bqkv + l * 3 * D, qkv, 3 * D, D, vT);
        if (l == L - 1)
            k_fattn<1><<<dim3(512 + CC), blk, 0, stream>>>(qkv, vT, aout, attnF,
                emb, embB, l * CC);
        else
            k_fattn<0><<<dim3(512 + CC), blk, 0, stream>>>(qkv, vT, aout, attnF,
                emb, embB, l * CC);
        k_gemm4<4, false><<<dim3(B * T / 128, D / 128, 4), blk, 0, stream>>>(
            aout, D, WTL + (size_t)3 * D * D, D, nullptr, pp, D, D / 4, nullptr);
        k_redlnT<4, false, true><<<dim3(B * T), blk, 0, stream>>>(pp, bproj + l * D, x,
            ln2g + l * D, ln2b + l * D, lnout, nullptr, nullptr, nullptr, nullptr, nullptr);
        k_gemm4<1, false><<<dim3(B * T / 128, F / 128), blk, 0, stream>>>(
            lnout, D, WTL + (size_t)4 * D * D, D, b1 + l * F, hmid, F, D, nullptr);
        k_gemm4<4, false><<<dim3(B * T / 128, D / 128, 4), blk, 0, stream>>>(
            hmid, F, WTL + (size_t)4 * D * D + D * F, F, nullptr, pp, D, F / 4, nullptr);
        if (l < L - 1) {
            k_redlnT<4, true, true><<<dim3(B * T + CG), blk, 0, stream>>>(pp, b2 + l * D, x,
                ln1g + (l + 1) * D, ln1b + (l + 1) * D, lnout,
                Wqkv + (size_t)(l + 1) * D * 3 * D, Wproj + (size_t)(l + 1) * D * D,
                W1 + (size_t)(l + 1) * D * F, W2 + (size_t)(l + 1) * F * D, WTL);
        } else {
            k_redlnT<4, false, false><<<dim3(B * T), blk, 0, stream>>>(pp, b2 + l * D, x,
                lnfg, lnfb, lnout, nullptr, nullptr, nullptr, nullptr, nullptr);
        }
    }
    k_gemm8<<<dim3(B * T / 256, V / 256), dim3(512), 0, stream>>>(
        lnout, D, embB, D, outb, logits, V, D);
}